// Round 22
// baseline (130.298 us; speedup 1.0000x reference)
//
#include <hip/hip_runtime.h>
#include <hip/hip_fp16.h>
#include <math.h>

#define IMG    512
#define TWD    64        // tile width
#define NSTRIP 2         // 32-row strips per block
#define BROWS  64        // output rows per block
#define WIN    42        // rolling hb window rows
#define HS2    34        // hb row stride in __half2 units (136 B)
#define NBLK   3072      // 8 * 8 * 48
#define NPIX   12582912.0

// Normalized 11-tap Gaussian, sigma=1.5 — inline literals
constexpr float G[11] = {
    0.00102838f, 0.00759876f, 0.03600077f, 0.10936069f, 0.21300554f,
    0.26601173f,
    0.21300554f, 0.10936069f, 0.03600077f, 0.00759876f, 0.00102838f};

// Clamped raw loads of 6 float4 per array (group all-valid or all-invalid,
// masked at consume time). Straight-line, no CFG.
__device__ __forceinline__ void issue_loads(
    const float* __restrict__ px, const float* __restrict__ py, int gc0,
    float4 (&fx)[6], float4 (&fy)[6])
{
#pragma unroll
    for (int i = 0; i < 6; ++i) {
        int gcl = min(max(gc0 + 4 * i, 0), IMG - 4);
        fx[i] = *(const float4*)(px + gcl);
        fy[i] = *(const float4*)(py + gcl);
    }
}

// h-conv (fp32) of one row x 8 outputs, packed to half2 and stored to LDS.
// fp32 accumulation + single fp16 quantization at store is the accuracy
// anchor (R18's fp16 running sum failed the absmax gate; R19's fp16
// pre-conv product quantization doubled the error margin).
__device__ __forceinline__ void conv_store(
    __half2 (&hb2)[4][WIN][HS2],
    const float4 (&fx)[6], const float4 (&fy)[6],
    int grow, int gc0, int bufrow, int hg)
{
    const float rm = ((unsigned)grow < IMG) ? 1.f : 0.f;
    float ax[8] = {}, ay[8] = {}, ass[8] = {}, axy[8] = {};
#pragma unroll
    for (int i = 0; i < 6; ++i) {
        const float gm = ((unsigned)(gc0 + 4 * i) < IMG) ? rm : 0.f;
        const float vx4[4] = {fx[i].x, fx[i].y, fx[i].z, fx[i].w};
        const float vy4[4] = {fy[i].x, fy[i].y, fy[i].z, fy[i].w};
#pragma unroll
        for (int c = 0; c < 4; ++c) {
            const int j = 4 * i + c;          // raw col idx 0..23
            if (j < 3 || j > 20) continue;    // compile-time pruned
            const float a  = vx4[c] * gm;
            const float b  = vy4[c] * gm;
            const float ss = fmaf(a, a, b * b);
            const float xy = a * b;
#pragma unroll
            for (int e = 0; e < 8; ++e) {
                const int k = j - 3 - e;      // tap index, compile-time
                if (k >= 0 && k <= 10) {
                    ax[e]  = fmaf(G[k], a,  ax[e]);
                    ay[e]  = fmaf(G[k], b,  ay[e]);
                    ass[e] = fmaf(G[k], ss, ass[e]);
                    axy[e] = fmaf(G[k], xy, axy[e]);
                }
            }
        }
    }
    const int p0 = 4 * hg;                    // first half2 col of this task
#pragma unroll
    for (int p = 0; p < 4; ++p) {
        hb2[0][bufrow][p0 + p] = __floats2half2_rn(ax[2*p],  ax[2*p+1]);
        hb2[1][bufrow][p0 + p] = __floats2half2_rn(ay[2*p],  ay[2*p+1]);
        hb2[2][bufrow][p0 + p] = __floats2half2_rn(ass[2*p], ass[2*p+1]);
        hb2[3][bufrow][p0 + p] = __floats2half2_rn(axy[2*p], axy[2*p+1]);
    }
}

// v-pass: 2 cols (one half2) x 4 rows, packed __hfma2 conv, SSIM in fp32.
__device__ __forceinline__ float vpass16(
    const __half2 (&hb2)[4][WIN][HS2], const __half2 (&Gh)[11],
    int rb, int cg)
{
    __half2 vr[4][4];
    const __half2 z2 = __floats2half2_rn(0.f, 0.f);
#pragma unroll
    for (int q = 0; q < 4; ++q)
#pragma unroll
        for (int j = 0; j < 4; ++j) vr[q][j] = z2;
#pragma unroll
    for (int q = 0; q < 4; ++q)
#pragma unroll
        for (int k = 0; k < 14; ++k) {
            __half2 v = hb2[q][rb + k][cg];
#pragma unroll
            for (int j = 0; j < 4; ++j)
                if (k - j >= 0 && k - j <= 10)
                    vr[q][j] = __hfma2(Gh[k - j], v, vr[q][j]);
        }
    float s = 0.f;
#pragma unroll
    for (int j = 0; j < 4; ++j) {
        float2 mxv  = __half22float2(vr[0][j]);
        float2 myv  = __half22float2(vr[1][j]);
        float2 mssv = __half22float2(vr[2][j]);
        float2 mxyv = __half22float2(vr[3][j]);
        const float mxa[2]  = {mxv.x, mxv.y};
        const float mya[2]  = {myv.x, myv.y};
        const float mssa[2] = {mssv.x, mssv.y};
        const float mxya[2] = {mxyv.x, mxyv.y};
#pragma unroll
        for (int e = 0; e < 2; ++e) {
            float mx = mxa[e], my = mya[e];
            float mss = mssa[e], mxy = mxya[e];
            float mx2 = mx * mx, my2 = my * my, mxmy = mx * my;
            float num = (2.f * mxmy + 0.0001f) * (2.f * (mxy - mxmy) + 0.0009f);
            float den = (mx2 + my2 + 0.0001f) * ((mss - mx2 - my2) + 0.0009f);
            s += num * __builtin_amdgcn_rcpf(den);
        }
    }
    return s;
}

// Champion structure (R17/R21) + fused last-block finalize:
// 2-strip rolling fp16 window, T14 register prefetch, XCD chunk swizzle,
// single masked code path. The block drawing the last ticket reduces all
// partials (fixed order, double accum -> deterministic regardless of which
// block wins) and writes out. Plain __launch_bounds__(256) — a min-wave
// hint caps VGPRs (84) and forces scratch traffic (R8-R12).
__global__ __launch_bounds__(256) void ssim_tile_kernel(
    const float* __restrict__ x, const float* __restrict__ y,
    float* __restrict__ partial, unsigned* __restrict__ count,
    float* __restrict__ out)
{
    __shared__ __half2 hb2[4][WIN][HS2];   // 22.3 KB
    __shared__ float wsum[4];
    __shared__ unsigned ticket;
    __shared__ double dsum[4];

    const int tid = threadIdx.x;
    const int bid = blockIdx.x;
    const int nb  = (bid & 7) * (NBLK / 8) + (bid >> 3);  // XCD chunk swizzle
    const int z   = nb >> 6;               // image 0..47 (64 blocks/image)
    const int rem = nb & 63;
    const int by  = rem >> 3, bx = rem & 7;
    const int c0 = bx * TWD;
    const int rbase0 = by * BROWS;
    const size_t ioff = (size_t)z * IMG * IMG;
    const float* __restrict__ xb = x + ioff;
    const float* __restrict__ yb = y + ioff;

    __half2 Gh[11];
#pragma unroll
    for (int k = 0; k < 11; ++k) Gh[k] = __floats2half2_rn(G[k], G[k]);

    const int hrow = tid >> 3;          // h-task row 0..31 (s>=1)
    const int hg   = tid & 7;           // 8-output col group
    const int gc0  = c0 - 8 + 8 * hg;   // first of 24 raw cols
    const int cg   = tid & 31;          // v-pass half2 col (cols 2cg,2cg+1)
    const int rb   = (tid >> 5) * 4;    // v-pass rows rb..rb+3
    float lsum = 0.f;

    float4 pfx[6], pfy[6];              // next-strip prefetch registers

    // ---- strip 0: fill all 42 window rows (336 tasks, 2 rounds) ----
    {
        int brow = tid >> 3, g = tid & 7;
        int grow = rbase0 - 5 + brow;
        int tg0 = c0 - 8 + 8 * g;
        const float* px = xb + min(max(grow, 0), IMG - 1) * IMG;
        const float* py = yb + min(max(grow, 0), IMG - 1) * IMG;
        float4 fx[6], fy[6];
        issue_loads(px, py, tg0, fx, fy);
        conv_store(hb2, fx, fy, grow, tg0, brow, g);
    }
    if (tid < 80) {
        int t = tid + 256;
        int brow = t >> 3, g = t & 7;
        int grow = rbase0 - 5 + brow;
        int tg0 = c0 - 8 + 8 * g;
        const float* px = xb + min(max(grow, 0), IMG - 1) * IMG;
        const float* py = yb + min(max(grow, 0), IMG - 1) * IMG;
        float4 fx[6], fy[6];
        issue_loads(px, py, tg0, fx, fy);
        conv_store(hb2, fx, fy, grow, tg0, brow, g);
    }
    // T14 prefetch of strip 1 rows (consumed after v-pass + carry)
    {
        int grow = rbase0 + 32 + 5 + hrow;
        const float* px = xb + min(max(grow, 0), IMG - 1) * IMG;
        const float* py = yb + min(max(grow, 0), IMG - 1) * IMG;
        issue_loads(px, py, gc0, pfx, pfy);
    }
    __syncthreads();
    lsum += vpass16(hb2, Gh, rb, cg);
    __syncthreads();

    for (int s = 1; s < NSTRIP; ++s) {
        // carry rows 32..41 -> 0..9 : 640 b64 moves (2 half2 each)
#pragma unroll
        for (int k = 0; k < 3; ++k) {
            int idx = tid + k * 256;
            if (idx < 640) {
                int q = idx / 160, rem2 = idx - q * 160;
                int rr = rem2 >> 4, p = rem2 & 15;
                *(float2*)&hb2[q][rr][2 * p] =
                    *(const float2*)&hb2[q][32 + rr][2 * p];
            }
        }
        __syncthreads();
        // h-conv from prefetched regs -> window rows 10..41
        {
            int grow = rbase0 + 32 * s + 5 + hrow;
            conv_store(hb2, pfx, pfy, grow, gc0, 10 + hrow, hg);
        }
        if (s < NSTRIP - 1) {
            int grow = rbase0 + 32 * (s + 1) + 5 + hrow;
            const float* px = xb + min(max(grow, 0), IMG - 1) * IMG;
            const float* py = yb + min(max(grow, 0), IMG - 1) * IMG;
            issue_loads(px, py, gc0, pfx, pfy);
        }
        __syncthreads();
        lsum += vpass16(hb2, Gh, rb, cg);
        __syncthreads();
    }

    // ---- block reduction -> partial store + last-block ticket ----
#pragma unroll
    for (int off = 32; off > 0; off >>= 1)
        lsum += __shfl_down(lsum, off, 64);
    if ((tid & 63) == 0) wsum[tid >> 6] = lsum;
    __syncthreads();
    if (tid == 0) {
        partial[bid] = wsum[0] + wsum[1] + wsum[2] + wsum[3];
        __threadfence();                       // release partial before ticket
        ticket = atomicAdd(count, 1u);         // device-scope RMW
    }
    __syncthreads();
    if (ticket == NBLK - 1) {
        // last block: all 3071 other partials are visible (each producer
        // fenced before its increment; atomic chain orders them all).
        __threadfence();                       // acquire
        double s = 0.0;
#pragma unroll
        for (int i = 0; i < NBLK / 256; ++i)
            s += (double)partial[tid + i * 256];
#pragma unroll
        for (int off = 32; off > 0; off >>= 1)
            s += __shfl_down(s, off, 64);
        if ((tid & 63) == 0) dsum[tid >> 6] = s;
        __syncthreads();
        if (tid == 0) {
            double t = dsum[0] + dsum[1] + dsum[2] + dsum[3];
            double mean = t / NPIX;
            out[0] = (float)(-log10(mean));    // loss
            out[1] = (float)mean;              // ssim_mean
        }
    }
}

extern "C" void kernel_launch(void* const* d_in, const int* in_sizes, int n_in,
                              void* d_out, int out_size, void* d_ws, size_t ws_size,
                              hipStream_t stream)
{
    const float* x = (const float*)d_in[0];
    const float* y = (const float*)d_in[1];
    float* out     = (float*)d_out;
    float* partial = (float*)d_ws;            // 3072 floats, rewritten each call
    unsigned* cnt  = (unsigned*)((char*)d_ws + NBLK * sizeof(float));

    hipMemsetAsync(cnt, 0, sizeof(unsigned), stream);   // graph-capture-safe
    ssim_tile_kernel<<<NBLK, 256, 0, stream>>>(x, y, partial, cnt, out);
}

// Round 23
// 51.219 us; speedup vs baseline: 2.5439x; 2.5439x over previous
//
#include <hip/hip_runtime.h>
#include <hip/hip_fp16.h>
#include <math.h>

#define IMG    512
#define TWD    64        // tile width
#define NSTRIP 2         // 32-row strips per block
#define BROWS  64        // output rows per block
#define WIN    42        // rolling hb window rows
#define HS2    34        // hb row stride in __half2 units (136 B)
#define NBLK   3072      // 8 * 8 * 48
#define NPIX   12582912.0

// Normalized 11-tap Gaussian, sigma=1.5 — inline literals
constexpr float G[11] = {
    0.00102838f, 0.00759876f, 0.03600077f, 0.10936069f, 0.21300554f,
    0.26601173f,
    0.21300554f, 0.10936069f, 0.03600077f, 0.00759876f, 0.00102838f};

// Clamped raw loads of 6 float4 per array (group all-valid or all-invalid,
// masked at consume time). Straight-line, no CFG.
__device__ __forceinline__ void issue_loads(
    const float* __restrict__ px, const float* __restrict__ py, int gc0,
    float4 (&fx)[6], float4 (&fy)[6])
{
#pragma unroll
    for (int i = 0; i < 6; ++i) {
        int gcl = min(max(gc0 + 4 * i, 0), IMG - 4);
        fx[i] = *(const float4*)(px + gcl);
        fy[i] = *(const float4*)(py + gcl);
    }
}

// h-conv (fp32) of one row x 8 outputs, packed to half2 and stored to LDS.
// fp32 accumulation + single fp16 quantization at store is the accuracy
// anchor (R18's fp16 running sum failed the absmax gate; R19's fp16
// pre-conv product quantization doubled the error margin).
__device__ __forceinline__ void conv_store(
    __half2 (&hb2)[4][WIN][HS2],
    const float4 (&fx)[6], const float4 (&fy)[6],
    int grow, int gc0, int bufrow, int hg)
{
    const float rm = ((unsigned)grow < IMG) ? 1.f : 0.f;
    float ax[8] = {}, ay[8] = {}, ass[8] = {}, axy[8] = {};
#pragma unroll
    for (int i = 0; i < 6; ++i) {
        const float gm = ((unsigned)(gc0 + 4 * i) < IMG) ? rm : 0.f;
        const float vx4[4] = {fx[i].x, fx[i].y, fx[i].z, fx[i].w};
        const float vy4[4] = {fy[i].x, fy[i].y, fy[i].z, fy[i].w};
#pragma unroll
        for (int c = 0; c < 4; ++c) {
            const int j = 4 * i + c;          // raw col idx 0..23
            if (j < 3 || j > 20) continue;    // compile-time pruned
            const float a  = vx4[c] * gm;
            const float b  = vy4[c] * gm;
            const float ss = fmaf(a, a, b * b);
            const float xy = a * b;
#pragma unroll
            for (int e = 0; e < 8; ++e) {
                const int k = j - 3 - e;      // tap index, compile-time
                if (k >= 0 && k <= 10) {
                    ax[e]  = fmaf(G[k], a,  ax[e]);
                    ay[e]  = fmaf(G[k], b,  ay[e]);
                    ass[e] = fmaf(G[k], ss, ass[e]);
                    axy[e] = fmaf(G[k], xy, axy[e]);
                }
            }
        }
    }
    const int p0 = 4 * hg;                    // first half2 col of this task
#pragma unroll
    for (int p = 0; p < 4; ++p) {
        hb2[0][bufrow][p0 + p] = __floats2half2_rn(ax[2*p],  ax[2*p+1]);
        hb2[1][bufrow][p0 + p] = __floats2half2_rn(ay[2*p],  ay[2*p+1]);
        hb2[2][bufrow][p0 + p] = __floats2half2_rn(ass[2*p], ass[2*p+1]);
        hb2[3][bufrow][p0 + p] = __floats2half2_rn(axy[2*p], axy[2*p+1]);
    }
}

// v-pass: 2 cols (one half2) x 4 rows, packed __hfma2 conv, SSIM in fp32.
__device__ __forceinline__ float vpass16(
    const __half2 (&hb2)[4][WIN][HS2], const __half2 (&Gh)[11],
    int rb, int cg)
{
    __half2 vr[4][4];
    const __half2 z2 = __floats2half2_rn(0.f, 0.f);
#pragma unroll
    for (int q = 0; q < 4; ++q)
#pragma unroll
        for (int j = 0; j < 4; ++j) vr[q][j] = z2;
#pragma unroll
    for (int q = 0; q < 4; ++q)
#pragma unroll
        for (int k = 0; k < 14; ++k) {
            __half2 v = hb2[q][rb + k][cg];
#pragma unroll
            for (int j = 0; j < 4; ++j)
                if (k - j >= 0 && k - j <= 10)
                    vr[q][j] = __hfma2(Gh[k - j], v, vr[q][j]);
        }
    float s = 0.f;
#pragma unroll
    for (int j = 0; j < 4; ++j) {
        float2 mxv  = __half22float2(vr[0][j]);
        float2 myv  = __half22float2(vr[1][j]);
        float2 mssv = __half22float2(vr[2][j]);
        float2 mxyv = __half22float2(vr[3][j]);
        const float mxa[2]  = {mxv.x, mxv.y};
        const float mya[2]  = {myv.x, myv.y};
        const float mssa[2] = {mssv.x, mssv.y};
        const float mxya[2] = {mxyv.x, mxyv.y};
#pragma unroll
        for (int e = 0; e < 2; ++e) {
            float mx = mxa[e], my = mya[e];
            float mss = mssa[e], mxy = mxya[e];
            float mx2 = mx * mx, my2 = my * my, mxmy = mx * my;
            float num = (2.f * mxmy + 0.0001f) * (2.f * (mxy - mxmy) + 0.0009f);
            float den = (mx2 + my2 + 0.0001f) * ((mss - mx2 - my2) + 0.0009f);
            s += num * __builtin_amdgcn_rcpf(den);
        }
    }
    return s;
}

// FINAL champion (R17/R21): 2-strip rolling fp16 window, T14 register
// prefetch, XCD chunk swizzle (halves FETCH: 93->49 MB), single masked
// code path (dual-template per-strip dispatch caused R16's front-end
// regression). Separate reduce kernel (fused last-block finalize with
// threadfence+atomic ticket regressed 2.5x in R22). Plain
// __launch_bounds__(256) — a min-wave hint caps VGPRs (84) and forces
// scratch traffic (R8-R12: 20-166 MB WRITE_SIZE).
__global__ __launch_bounds__(256) void ssim_tile_kernel(
    const float* __restrict__ x, const float* __restrict__ y,
    float* __restrict__ partial)
{
    __shared__ __half2 hb2[4][WIN][HS2];   // 22.3 KB
    __shared__ float wsum[4];

    const int tid = threadIdx.x;
    const int bid = blockIdx.x;
    const int nb  = (bid & 7) * (NBLK / 8) + (bid >> 3);  // XCD chunk swizzle
    const int z   = nb >> 6;               // image 0..47 (64 blocks/image)
    const int rem = nb & 63;
    const int by  = rem >> 3, bx = rem & 7;
    const int c0 = bx * TWD;
    const int rbase0 = by * BROWS;
    const size_t ioff = (size_t)z * IMG * IMG;
    const float* __restrict__ xb = x + ioff;
    const float* __restrict__ yb = y + ioff;

    __half2 Gh[11];
#pragma unroll
    for (int k = 0; k < 11; ++k) Gh[k] = __floats2half2_rn(G[k], G[k]);

    const int hrow = tid >> 3;          // h-task row 0..31 (s>=1)
    const int hg   = tid & 7;           // 8-output col group
    const int gc0  = c0 - 8 + 8 * hg;   // first of 24 raw cols
    const int cg   = tid & 31;          // v-pass half2 col (cols 2cg,2cg+1)
    const int rb   = (tid >> 5) * 4;    // v-pass rows rb..rb+3
    float lsum = 0.f;

    float4 pfx[6], pfy[6];              // next-strip prefetch registers

    // ---- strip 0: fill all 42 window rows (336 tasks, 2 rounds) ----
    {
        int brow = tid >> 3, g = tid & 7;
        int grow = rbase0 - 5 + brow;
        int tg0 = c0 - 8 + 8 * g;
        const float* px = xb + min(max(grow, 0), IMG - 1) * IMG;
        const float* py = yb + min(max(grow, 0), IMG - 1) * IMG;
        float4 fx[6], fy[6];
        issue_loads(px, py, tg0, fx, fy);
        conv_store(hb2, fx, fy, grow, tg0, brow, g);
    }
    if (tid < 80) {
        int t = tid + 256;
        int brow = t >> 3, g = t & 7;
        int grow = rbase0 - 5 + brow;
        int tg0 = c0 - 8 + 8 * g;
        const float* px = xb + min(max(grow, 0), IMG - 1) * IMG;
        const float* py = yb + min(max(grow, 0), IMG - 1) * IMG;
        float4 fx[6], fy[6];
        issue_loads(px, py, tg0, fx, fy);
        conv_store(hb2, fx, fy, grow, tg0, brow, g);
    }
    // T14 prefetch of strip 1 rows (consumed after v-pass + carry)
    {
        int grow = rbase0 + 32 + 5 + hrow;
        const float* px = xb + min(max(grow, 0), IMG - 1) * IMG;
        const float* py = yb + min(max(grow, 0), IMG - 1) * IMG;
        issue_loads(px, py, gc0, pfx, pfy);
    }
    __syncthreads();
    lsum += vpass16(hb2, Gh, rb, cg);
    __syncthreads();

    for (int s = 1; s < NSTRIP; ++s) {
        // carry rows 32..41 -> 0..9 : 640 b64 moves (2 half2 each)
#pragma unroll
        for (int k = 0; k < 3; ++k) {
            int idx = tid + k * 256;
            if (idx < 640) {
                int q = idx / 160, rem2 = idx - q * 160;
                int rr = rem2 >> 4, p = rem2 & 15;
                *(float2*)&hb2[q][rr][2 * p] =
                    *(const float2*)&hb2[q][32 + rr][2 * p];
            }
        }
        __syncthreads();
        // h-conv from prefetched regs -> window rows 10..41
        {
            int grow = rbase0 + 32 * s + 5 + hrow;
            conv_store(hb2, pfx, pfy, grow, gc0, 10 + hrow, hg);
        }
        if (s < NSTRIP - 1) {
            int grow = rbase0 + 32 * (s + 1) + 5 + hrow;
            const float* px = xb + min(max(grow, 0), IMG - 1) * IMG;
            const float* py = yb + min(max(grow, 0), IMG - 1) * IMG;
            issue_loads(px, py, gc0, pfx, pfy);
        }
        __syncthreads();
        lsum += vpass16(hb2, Gh, rb, cg);
        __syncthreads();
    }

    // ---- block reduction -> plain store ----
#pragma unroll
    for (int off = 32; off > 0; off >>= 1)
        lsum += __shfl_down(lsum, off, 64);
    if ((tid & 63) == 0) wsum[tid >> 6] = lsum;
    __syncthreads();
    if (tid == 0)
        partial[bid] = wsum[0] + wsum[1] + wsum[2] + wsum[3];
}

__global__ __launch_bounds__(1024) void ssim_reduce_kernel(
    const float* __restrict__ partial, float* __restrict__ out)
{
    __shared__ double ws[16];
    const int tid = threadIdx.x;
    double s = 0.0;
#pragma unroll
    for (int i = 0; i < NBLK / 1024; ++i) s += (double)partial[tid + i * 1024];
#pragma unroll
    for (int off = 32; off > 0; off >>= 1)
        s += __shfl_down(s, off, 64);
    if ((tid & 63) == 0) ws[tid >> 6] = s;
    __syncthreads();
    if (tid == 0) {
        double t = 0.0;
#pragma unroll
        for (int w = 0; w < 16; ++w) t += ws[w];
        double mean = t / NPIX;
        out[0] = (float)(-log10(mean));  // loss
        out[1] = (float)mean;            // ssim_mean
    }
}

extern "C" void kernel_launch(void* const* d_in, const int* in_sizes, int n_in,
                              void* d_out, int out_size, void* d_ws, size_t ws_size,
                              hipStream_t stream)
{
    const float* x = (const float*)d_in[0];
    const float* y = (const float*)d_in[1];
    float* out     = (float*)d_out;
    float* partial = (float*)d_ws;      // 3072 floats, fully rewritten each call

    ssim_tile_kernel<<<NBLK, 256, 0, stream>>>(x, y, partial);
    ssim_reduce_kernel<<<1, 1024, 0, stream>>>(partial, out);
}

// Round 24
// 45.000 us; speedup vs baseline: 2.8955x; 1.1382x over previous
//
#include <hip/hip_runtime.h>
#include <hip/hip_fp16.h>
#include <math.h>

#define IMG    512
#define TWD    64        // tile width
#define NSTRIP 2         // 32-row strips per block
#define BROWS  64        // output rows per block
#define WIN    42        // rolling hb window rows
#define HS2    34        // hb row stride in __half2 units (136 B)
#define NBLK   3072      // 8 * 8 * 48
#define NPIX   12582912.0

// Normalized 11-tap Gaussian, sigma=1.5 — inline literals
constexpr float G[11] = {
    0.00102838f, 0.00759876f, 0.03600077f, 0.10936069f, 0.21300554f,
    0.26601173f,
    0.21300554f, 0.10936069f, 0.03600077f, 0.00759876f, 0.00102838f};

typedef float f32x2 __attribute__((ext_vector_type(2)));

// Clamped raw loads of 6 float4 per array (group all-valid or all-invalid,
// masked at consume time). Straight-line, no CFG.
__device__ __forceinline__ void issue_loads(
    const float* __restrict__ px, const float* __restrict__ py, int gc0,
    float4 (&fx)[6], float4 (&fy)[6])
{
#pragma unroll
    for (int i = 0; i < 6; ++i) {
        int gcl = min(max(gc0 + 4 * i, 0), IMG - 4);
        fx[i] = *(const float4*)(px + gcl);
        fy[i] = *(const float4*)(py + gcl);
    }
}

// h-conv (fp32) of one row x 8 outputs, PLANE-PAIR PACKED:
// mv[m]=(x,y), pc[m]=(x^2+y^2, x*y); all four convolutions share G[k] and
// the sliding index, so each v_pk_fma_f32 does two planes at once with no
// shuffle overhead. Per-lane pk_fma is IEEE fp32 -> bit-identical to the
// scalar champion (same op order). fp32 accumulation + single fp16
// quantization at store is the accuracy anchor (R18/R19 lessons).
__device__ __forceinline__ void conv_store(
    __half2 (&hb2)[4][WIN][HS2],
    const float4 (&fx)[6], const float4 (&fy)[6],
    int grow, int gc0, int bufrow, int hg)
{
    const float rm = ((unsigned)grow < IMG) ? 1.f : 0.f;
    f32x2 mv[18], pc[18];                     // raw cols 3..20 -> m 0..17
#pragma unroll
    for (int i = 0; i < 6; ++i) {
        const float gm = ((unsigned)(gc0 + 4 * i) < IMG) ? rm : 0.f;
        const float vx4[4] = {fx[i].x, fx[i].y, fx[i].z, fx[i].w};
        const float vy4[4] = {fy[i].x, fy[i].y, fy[i].z, fy[i].w};
#pragma unroll
        for (int c = 0; c < 4; ++c) {
            const int j = 4 * i + c;          // raw col idx 0..23
            if (j < 3 || j > 20) continue;    // compile-time pruned
            const float a = vx4[c] * gm;
            const float b = vy4[c] * gm;
            mv[j - 3] = (f32x2){a, b};
            pc[j - 3] = (f32x2){fmaf(a, a, b * b), a * b};
        }
    }
    f32x2 am[8], ap[8];
#pragma unroll
    for (int e = 0; e < 8; ++e) {
        am[e] = (f32x2){0.f, 0.f};
        ap[e] = (f32x2){0.f, 0.f};
    }
#pragma unroll
    for (int e = 0; e < 8; ++e)
#pragma unroll
        for (int k = 0; k < 11; ++k) {
            const f32x2 gk = {G[k], G[k]};
            am[e] = __builtin_elementwise_fma(gk, mv[e + k], am[e]);
            ap[e] = __builtin_elementwise_fma(gk, pc[e + k], ap[e]);
        }
    const int p0 = 4 * hg;                    // first half2 col of this task
#pragma unroll
    for (int p = 0; p < 4; ++p) {
        hb2[0][bufrow][p0 + p] = __floats2half2_rn(am[2*p].x, am[2*p+1].x);
        hb2[1][bufrow][p0 + p] = __floats2half2_rn(am[2*p].y, am[2*p+1].y);
        hb2[2][bufrow][p0 + p] = __floats2half2_rn(ap[2*p].x, ap[2*p+1].x);
        hb2[3][bufrow][p0 + p] = __floats2half2_rn(ap[2*p].y, ap[2*p+1].y);
    }
}

// v-pass: 2 cols (one half2) x 4 rows, packed __hfma2 conv, SSIM in fp32.
__device__ __forceinline__ float vpass16(
    const __half2 (&hb2)[4][WIN][HS2], const __half2 (&Gh)[11],
    int rb, int cg)
{
    __half2 vr[4][4];
    const __half2 z2 = __floats2half2_rn(0.f, 0.f);
#pragma unroll
    for (int q = 0; q < 4; ++q)
#pragma unroll
        for (int j = 0; j < 4; ++j) vr[q][j] = z2;
#pragma unroll
    for (int q = 0; q < 4; ++q)
#pragma unroll
        for (int k = 0; k < 14; ++k) {
            __half2 v = hb2[q][rb + k][cg];
#pragma unroll
            for (int j = 0; j < 4; ++j)
                if (k - j >= 0 && k - j <= 10)
                    vr[q][j] = __hfma2(Gh[k - j], v, vr[q][j]);
        }
    float s = 0.f;
#pragma unroll
    for (int j = 0; j < 4; ++j) {
        float2 mxv  = __half22float2(vr[0][j]);
        float2 myv  = __half22float2(vr[1][j]);
        float2 mssv = __half22float2(vr[2][j]);
        float2 mxyv = __half22float2(vr[3][j]);
        const float mxa[2]  = {mxv.x, mxv.y};
        const float mya[2]  = {myv.x, myv.y};
        const float mssa[2] = {mssv.x, mssv.y};
        const float mxya[2] = {mxyv.x, mxyv.y};
#pragma unroll
        for (int e = 0; e < 2; ++e) {
            float mx = mxa[e], my = mya[e];
            float mss = mssa[e], mxy = mxya[e];
            float mx2 = mx * mx, my2 = my * my, mxmy = mx * my;
            float num = (2.f * mxmy + 0.0001f) * (2.f * (mxy - mxmy) + 0.0009f);
            float den = (mx2 + my2 + 0.0001f) * ((mss - mx2 - my2) + 0.0009f);
            s += num * __builtin_amdgcn_rcpf(den);
        }
    }
    return s;
}

// Champion structure (R17/R21): 2-strip rolling fp16 window, T14 register
// prefetch, XCD chunk swizzle (halves FETCH: 93->49 MB), single masked
// code path. Separate reduce kernel (fused finalize regressed 2.5x, R22).
// Plain __launch_bounds__(256) — a min-wave hint caps VGPRs and forces
// scratch traffic (R8-R12: 20-166 MB WRITE_SIZE).
__global__ __launch_bounds__(256) void ssim_tile_kernel(
    const float* __restrict__ x, const float* __restrict__ y,
    float* __restrict__ partial)
{
    __shared__ __half2 hb2[4][WIN][HS2];   // 22.3 KB
    __shared__ float wsum[4];

    const int tid = threadIdx.x;
    const int bid = blockIdx.x;
    const int nb  = (bid & 7) * (NBLK / 8) + (bid >> 3);  // XCD chunk swizzle
    const int z   = nb >> 6;               // image 0..47 (64 blocks/image)
    const int rem = nb & 63;
    const int by  = rem >> 3, bx = rem & 7;
    const int c0 = bx * TWD;
    const int rbase0 = by * BROWS;
    const size_t ioff = (size_t)z * IMG * IMG;
    const float* __restrict__ xb = x + ioff;
    const float* __restrict__ yb = y + ioff;

    __half2 Gh[11];
#pragma unroll
    for (int k = 0; k < 11; ++k) Gh[k] = __floats2half2_rn(G[k], G[k]);

    const int hrow = tid >> 3;          // h-task row 0..31 (s>=1)
    const int hg   = tid & 7;           // 8-output col group
    const int gc0  = c0 - 8 + 8 * hg;   // first of 24 raw cols
    const int cg   = tid & 31;          // v-pass half2 col (cols 2cg,2cg+1)
    const int rb   = (tid >> 5) * 4;    // v-pass rows rb..rb+3
    float lsum = 0.f;

    float4 pfx[6], pfy[6];              // next-strip prefetch registers

    // ---- strip 0: fill all 42 window rows (336 tasks, 2 rounds) ----
    {
        int brow = tid >> 3, g = tid & 7;
        int grow = rbase0 - 5 + brow;
        int tg0 = c0 - 8 + 8 * g;
        const float* px = xb + min(max(grow, 0), IMG - 1) * IMG;
        const float* py = yb + min(max(grow, 0), IMG - 1) * IMG;
        float4 fx[6], fy[6];
        issue_loads(px, py, tg0, fx, fy);
        conv_store(hb2, fx, fy, grow, tg0, brow, g);
    }
    if (tid < 80) {
        int t = tid + 256;
        int brow = t >> 3, g = t & 7;
        int grow = rbase0 - 5 + brow;
        int tg0 = c0 - 8 + 8 * g;
        const float* px = xb + min(max(grow, 0), IMG - 1) * IMG;
        const float* py = yb + min(max(grow, 0), IMG - 1) * IMG;
        float4 fx[6], fy[6];
        issue_loads(px, py, tg0, fx, fy);
        conv_store(hb2, fx, fy, grow, tg0, brow, g);
    }
    // T14 prefetch of strip 1 rows (consumed after v-pass + carry)
    {
        int grow = rbase0 + 32 + 5 + hrow;
        const float* px = xb + min(max(grow, 0), IMG - 1) * IMG;
        const float* py = yb + min(max(grow, 0), IMG - 1) * IMG;
        issue_loads(px, py, gc0, pfx, pfy);
    }
    __syncthreads();
    lsum += vpass16(hb2, Gh, rb, cg);
    __syncthreads();

    for (int s = 1; s < NSTRIP; ++s) {
        // carry rows 32..41 -> 0..9 : 640 b64 moves (2 half2 each)
#pragma unroll
        for (int k = 0; k < 3; ++k) {
            int idx = tid + k * 256;
            if (idx < 640) {
                int q = idx / 160, rem2 = idx - q * 160;
                int rr = rem2 >> 4, p = rem2 & 15;
                *(float2*)&hb2[q][rr][2 * p] =
                    *(const float2*)&hb2[q][32 + rr][2 * p];
            }
        }
        __syncthreads();
        // h-conv from prefetched regs -> window rows 10..41
        {
            int grow = rbase0 + 32 * s + 5 + hrow;
            conv_store(hb2, pfx, pfy, grow, gc0, 10 + hrow, hg);
        }
        if (s < NSTRIP - 1) {
            int grow = rbase0 + 32 * (s + 1) + 5 + hrow;
            const float* px = xb + min(max(grow, 0), IMG - 1) * IMG;
            const float* py = yb + min(max(grow, 0), IMG - 1) * IMG;
            issue_loads(px, py, gc0, pfx, pfy);
        }
        __syncthreads();
        lsum += vpass16(hb2, Gh, rb, cg);
        __syncthreads();
    }

    // ---- block reduction -> plain store ----
#pragma unroll
    for (int off = 32; off > 0; off >>= 1)
        lsum += __shfl_down(lsum, off, 64);
    if ((tid & 63) == 0) wsum[tid >> 6] = lsum;
    __syncthreads();
    if (tid == 0)
        partial[bid] = wsum[0] + wsum[1] + wsum[2] + wsum[3];
}

__global__ __launch_bounds__(1024) void ssim_reduce_kernel(
    const float* __restrict__ partial, float* __restrict__ out)
{
    __shared__ double ws[16];
    const int tid = threadIdx.x;
    double s = 0.0;
#pragma unroll
    for (int i = 0; i < NBLK / 1024; ++i) s += (double)partial[tid + i * 1024];
#pragma unroll
    for (int off = 32; off > 0; off >>= 1)
        s += __shfl_down(s, off, 64);
    if ((tid & 63) == 0) ws[tid >> 6] = s;
    __syncthreads();
    if (tid == 0) {
        double t = 0.0;
#pragma unroll
        for (int w = 0; w < 16; ++w) t += ws[w];
        double mean = t / NPIX;
        out[0] = (float)(-log10(mean));  // loss
        out[1] = (float)mean;            // ssim_mean
    }
}

extern "C" void kernel_launch(void* const* d_in, const int* in_sizes, int n_in,
                              void* d_out, int out_size, void* d_ws, size_t ws_size,
                              hipStream_t stream)
{
    const float* x = (const float*)d_in[0];
    const float* y = (const float*)d_in[1];
    float* out     = (float*)d_out;
    float* partial = (float*)d_ws;      // 3072 floats, fully rewritten each call

    ssim_tile_kernel<<<NBLK, 256, 0, stream>>>(x, y, partial);
    ssim_reduce_kernel<<<1, 1024, 0, stream>>>(partial, out);
}